// Round 9
// baseline (939.989 us; speedup 1.0000x reference)
//
#include <hip/hip_runtime.h>
#include <math.h>

// Llama4TextMoe — round 9: depth-2 pipelined GEMMs (3 LDS buffers, counted vmcnt,
// raw barriers, NO sched_barrier pinning — r8 lesson / m141).
// Loop: STAGE(buf+2, tile kt+2) -> vmcnt(8|12) (drains tile kt only; kt+1/kt+2 in
// flight) -> s_barrier -> ds_read_b128 frags + MFMA -> s_barrier -> rotate ptrs.
// prep (validated r7): weights fp32[K][N] -> bf16[N][K]; X/XS -> bf16 slot-ordered.

#define BM 128
#define BN 64
#define BK 32
#define MAXT 32

typedef float f32x4 __attribute__((ext_vector_type(4)));
typedef short bf16x8 __attribute__((ext_vector_type(8)));
typedef __bf16 bf2 __attribute__((ext_vector_type(2)));

__device__ inline unsigned int pk2(float a, float b) {
    union { bf2 h; unsigned int u; } c;
    c.h[0] = (__bf16)a; c.h[1] = (__bf16)b;   // v_cvt_pk_bf16_f32
    return c.u;
}
__device__ inline unsigned short f2bf(float a) {
    union { __bf16 h; unsigned short u; } c; c.h = (__bf16)a; return c.u;
}
__device__ inline bf16x8 pk8(float4 a, float4 b) {
    union { bf16x8 v; unsigned int u[4]; } c;
    c.u[0] = pk2(a.x, a.y); c.u[1] = pk2(a.z, a.w);
    c.u[2] = pk2(b.x, b.y); c.u[3] = pk2(b.z, b.w);
    return c.v;
}

// global -> LDS DMA, 16B per lane; dest = (wave-uniform lds) + lane*16.
__device__ inline void gload16(const void* g, void* l) {
    __builtin_amdgcn_global_load_lds(
        (const __attribute__((address_space(1))) void*)(unsigned long long)g,
        (__attribute__((address_space(3))) void*)(unsigned int)(unsigned long long)l,
        16, 0, 0);
}

#define VMCNT8()  asm volatile("s_waitcnt vmcnt(8)" ::: "memory")
#define VMCNT12() asm volatile("s_waitcnt vmcnt(12)" ::: "memory")
#define BAR()     __builtin_amdgcn_s_barrier()

// ---------------- router / bookkeeping (validated) ----------------

__global__ __launch_bounds__(256) void router_kernel(
    const float* __restrict__ x, const float* __restrict__ rw,
    float* __restrict__ scores_out, int* __restrict__ eidx,
    float* __restrict__ score, int* __restrict__ counts, int T, int H, int E)
{
    int g = blockIdx.x * 256 + threadIdx.x;
    int t = g >> 3, e = g & 7;          // E == 8
    if (t >= T) return;
    const float4* xr4 = (const float4*)(x + (size_t)t * H);
    float acc = 0.f;
    for (int k4 = 0; k4 < H / 4; k4++) {
        float4 xv = xr4[k4];
        int k = 4 * k4;
        acc = fmaf(xv.x, rw[(k + 0) * E + e], acc);
        acc = fmaf(xv.y, rw[(k + 1) * E + e], acc);
        acc = fmaf(xv.z, rw[(k + 2) * E + e], acc);
        acc = fmaf(xv.w, rw[(k + 3) * E + e], acc);
    }
    float bv = acc; int bi = e;
    #pragma unroll
    for (int off = 4; off; off >>= 1) {
        float ov = __shfl_xor(bv, off, 8);
        int   oi = __shfl_xor(bi, off, 8);
        if (ov > bv || (ov == bv && oi < bi)) { bv = ov; bi = oi; }
    }
    float sig = 1.f / (1.f + __expf(-bv));
    scores_out[(size_t)e * T + t] = (e == bi) ? sig : 0.f;
    if (e == 0) {
        eidx[t] = bi;
        score[t] = sig;
        atomicAdd(&counts[bi], 1);
    }
}

__global__ void prefix_kernel(const int* __restrict__ counts, int* __restrict__ offs,
                              int* __restrict__ tile_e, int* __restrict__ tile_m,
                              int* __restrict__ ntile, int E)
{
    if (blockIdx.x == 0 && threadIdx.x == 0) {
        int run = 0, nt = 0;
        for (int e = 0; e < E; e++) {
            offs[e] = run;
            int c = counts[e];
            int t = (c + BM - 1) / BM;
            for (int i = 0; i < t; i++) { tile_e[nt] = e; tile_m[nt] = i * BM; nt++; }
            run += t * BM;
        }
        ntile[0] = nt;
    }
}

__global__ __launch_bounds__(256) void scatter_kernel(
    const int* __restrict__ eidx, const int* __restrict__ offs,
    int* __restrict__ cursor, int* __restrict__ list, int T)
{
    int t = blockIdx.x * 256 + threadIdx.x;
    if (t >= T) return;
    int e = eidx[t];
    int pos = offs[e] + atomicAdd(&cursor[e], 1);
    list[pos] = t;
}

// ---------------- prep: X -> bf16, XS (slot-ordered, scaled) -> bf16 ----------------

__global__ __launch_bounds__(256) void prep_x(
    const float* __restrict__ x, const int* __restrict__ list,
    const float* __restrict__ score, const int* __restrict__ counts,
    const int* __restrict__ offs,
    unsigned short* __restrict__ Xbf, unsigned short* __restrict__ XSbf,
    int T, int H, int E)
{
    int bid = blockIdx.x, tid = threadIdx.x;   // one block = one row; H/8 == 256
    if (bid < T) {
        const float* src = x + (size_t)bid * H + tid * 8;
        float4 a = *(const float4*)src, b = *(const float4*)(src + 4);
        *(bf16x8*)(Xbf + (size_t)bid * H + tid * 8) = pk8(a, b);
    } else {
        int s = bid - T;
        int tok = -1; float sc = 0.f;
        for (int e = 0; e < E; e++) {
            int pad = ((counts[e] + BM - 1) / BM) * BM;
            if (s >= offs[e] && s < offs[e] + pad) {
                if (s - offs[e] < counts[e]) { tok = list[s]; sc = score[tok]; }
                break;
            }
        }
        bf16x8 o;
        if (tok >= 0) {
            const float* src = x + (size_t)tok * H + tid * 8;
            float4 a = *(const float4*)src, b = *(const float4*)(src + 4);
            a.x *= sc; a.y *= sc; a.z *= sc; a.w *= sc;
            b.x *= sc; b.y *= sc; b.z *= sc; b.w *= sc;
            o = pk8(a, b);
        } else {
            o = (bf16x8){0,0,0,0,0,0,0,0};
        }
        *(bf16x8*)(XSbf + (size_t)s * H + tid * 8) = o;
    }
}

// ---------------- prep: W fp32 [B][K][N] -> bf16 [B][N][K] ----------------

__global__ __launch_bounds__(256) void transpose_cvt(
    const float* __restrict__ src, unsigned short* __restrict__ dst, int K, int N)
{
    __shared__ float t[64][65];
    src += (size_t)blockIdx.z * K * N;
    dst += (size_t)blockIdx.z * K * N;
    const int k0 = blockIdx.x * 64, n0 = blockIdx.y * 64;
    const int tid = threadIdx.x;
    const int r = tid >> 4, c = (tid & 15) * 4;
#pragma unroll
    for (int i = 0; i < 4; i++) {
        float4 v = *(const float4*)(src + (size_t)(k0 + r + 16 * i) * N + n0 + c);
        t[r + 16 * i][c + 0] = v.x; t[r + 16 * i][c + 1] = v.y;
        t[r + 16 * i][c + 2] = v.z; t[r + 16 * i][c + 3] = v.w;
    }
    __syncthreads();
    const int nl = tid >> 2, kq = (tid & 3) * 16;
    union { bf16x8 v[2]; unsigned short u[16]; } o;
#pragma unroll
    for (int j = 0; j < 16; j++) o.u[j] = f2bf(t[kq + j][nl]);
    unsigned short* d = dst + (size_t)(n0 + nl) * K + k0 + kq;
    *(bf16x8*)d = o.v[0];
    *(bf16x8*)(d + 8) = o.v[1];
}

// ---------------- up: merged shared+routed, depth-2 pipelined ----------------

__global__ __launch_bounds__(256) void up_gemm(
    const unsigned short* __restrict__ Xbf, const unsigned short* __restrict__ XSbf,
    const unsigned short* __restrict__ sgT, const unsigned short* __restrict__ suT,
    const unsigned short* __restrict__ gupT,
    const int* __restrict__ tile_e, const int* __restrict__ tile_m,
    const int* __restrict__ ntile, const int* __restrict__ offs,
    unsigned short* __restrict__ sharedH, unsigned short* __restrict__ routedH,
    int I, int T)
{
    const int K = 2048;
    const int nwg = gridDim.x * gridDim.y;
    const int hw = blockIdx.y * gridDim.x + blockIdx.x;
    const int q8 = nwg >> 3;                         // nwg % 8 == 0 by construction
    const int vid = (hw & 7) * q8 + (hw >> 3);
    const int gt = vid % gridDim.x;
    const int nb = vid / gridDim.x;
    const int TS = T / BM;

    const unsigned short *Ab, *Bg, *Bu;
    unsigned short* outP;
    int rowbase;
    if (gt < TS) {
        Ab = Xbf + (size_t)(gt * BM) * K;
        Bg = sgT + (size_t)(nb * BN) * K;
        Bu = suT + (size_t)(nb * BN) * K;
        rowbase = gt * BM; outP = sharedH;
    } else {
        int idx = gt - TS;
        if (idx >= ntile[0]) return;
        int e = tile_e[idx], mb = tile_m[idx], oe = offs[e];
        Ab = XSbf + (size_t)(oe + mb) * K;
        const unsigned short* W = gupT + (size_t)e * (2 * (size_t)I) * K;
        Bg = W + (size_t)(nb * BN) * K;
        Bu = W + (size_t)(I + nb * BN) * K;
        rowbase = oe + mb; outP = routedH;
    }

    __shared__ __attribute__((aligned(128))) short As0[BM * BK], As1[BM * BK], As2[BM * BK];
    __shared__ __attribute__((aligned(128))) short Gs0[BN * BK], Gs1[BN * BK], Gs2[BN * BK];
    __shared__ __attribute__((aligned(128))) short Us0[BN * BK], Us1[BN * BK], Us2[BN * BK];

    const int tid = threadIdx.x;
    const int lane = tid & 63, wid = tid >> 6;
    const int wr = wid >> 1, wc = wid & 1;
    const int l2 = lane >> 2, la3 = lane & 3, l15 = lane & 15;
    const int kh = (lane >> 4) * 8;

    const unsigned short* sA0 = Ab + (size_t)(16 * wid + l2) * K + la3 * 8;
    const unsigned short* sA1 = Ab + (size_t)(64 + 16 * wid + l2) * K + la3 * 8;
    const unsigned short* sG  = Bg + (size_t)(16 * wid + l2) * K + la3 * 8;
    const unsigned short* sU  = Bu + (size_t)(16 * wid + l2) * K + la3 * 8;
    const int wo = wid * 512;

    f32x4 accg[4][2], accu[4][2];
#pragma unroll
    for (int i = 0; i < 4; i++)
#pragma unroll
        for (int j = 0; j < 2; j++) {
            accg[i][j] = (f32x4){0.f, 0.f, 0.f, 0.f};
            accu[i][j] = (f32x4){0.f, 0.f, 0.f, 0.f};
        }

    auto STAGE = [&](short* Ab_, short* Gb_, short* Ub_, int k0) {
        gload16(sA0 + k0, Ab_ + wo); gload16(sA1 + k0, Ab_ + 2048 + wo);
        gload16(sG + k0, Gb_ + wo);  gload16(sU + k0, Ub_ + wo);
    };
    auto COMPUTE = [&](const short* Asb, const short* Gsb, const short* Usb) {
        bf16x8 af[4], gfr[2], ufr[2];
#pragma unroll
        for (int q = 0; q < 4; q++)
            af[q] = *(const bf16x8*)(Asb + (wr * 64 + q * 16 + l15) * BK + kh);
#pragma unroll
        for (int nj = 0; nj < 2; nj++) {
            gfr[nj] = *(const bf16x8*)(Gsb + (wc * 32 + nj * 16 + l15) * BK + kh);
            ufr[nj] = *(const bf16x8*)(Usb + (wc * 32 + nj * 16 + l15) * BK + kh);
        }
#pragma unroll
        for (int mi = 0; mi < 4; mi++)
#pragma unroll
            for (int nj = 0; nj < 2; nj++) {
                accg[mi][nj] = __builtin_amdgcn_mfma_f32_16x16x32_bf16(af[mi], gfr[nj], accg[mi][nj], 0, 0, 0);
                accu[mi][nj] = __builtin_amdgcn_mfma_f32_16x16x32_bf16(af[mi], ufr[nj], accu[mi][nj], 0, 0, 0);
            }
    };

    const int nK = K / BK;   // 64
    short *Ac = As0, *An = As1, *Aw = As2;
    short *Gc = Gs0, *Gn = Gs1, *Gw = Gs2;
    short *Uc = Us0, *Un = Us1, *Uw = Us2;
    STAGE(Ac, Gc, Uc, 0);
    STAGE(An, Gn, Un, BK);
    for (int kt = 0; kt < nK; kt++) {
        int kf = kt + 2; if (kf >= nK) kf -= nK;   // wrap: uniform count, harmless loads
        STAGE(Aw, Gw, Uw, kf * BK);
        VMCNT8(); BAR();
        COMPUTE(Ac, Gc, Uc);
        BAR();
        short* t;
        t = Ac; Ac = An; An = Aw; Aw = t;
        t = Gc; Gc = Gn; Gn = Gw; Gw = t;
        t = Uc; Uc = Un; Un = Uw; Uw = t;
    }

    const int rb = (lane >> 4) * 4, cb = l15;
#pragma unroll
    for (int mi = 0; mi < 4; mi++)
#pragma unroll
        for (int nj = 0; nj < 2; nj++) {
            int col = nb * BN + wc * 32 + nj * 16 + cb;
#pragma unroll
            for (int j = 0; j < 4; j++) {
                float g = accg[mi][nj][j], u = accu[mi][nj][j];
                float r = u * g * __builtin_amdgcn_rcpf(1.f + __expf(-g));
                int row = rowbase + wr * 64 + mi * 16 + rb + j;
                outP[(size_t)row * I + col] = f2bf(r);
            }
        }
}

// ---------------- fused down: out[tok] = SH[tok]@WsdT^T + RH[slot]@dpT_e^T ----------------

__global__ __launch_bounds__(256) void fused_down(
    const unsigned short* __restrict__ SH, const unsigned short* __restrict__ RH,
    const unsigned short* __restrict__ WsdT, const unsigned short* __restrict__ dpT,
    const int* __restrict__ counts, const int* __restrict__ offs,
    const int* __restrict__ list,
    const int* __restrict__ tile_e, const int* __restrict__ tile_m,
    const int* __restrict__ ntile,
    float* __restrict__ out, int I, int H)
{
    const int nwg = gridDim.x * gridDim.y;
    const int hw = blockIdx.y * gridDim.x + blockIdx.x;
    const int q8 = nwg >> 3;
    const int vid = (hw & 7) * q8 + (hw >> 3);
    const int gt = vid % gridDim.x;
    const int nb = vid / gridDim.x;
    if (gt >= ntile[0]) return;
    const int e = tile_e[gt], mbase = tile_m[gt];
    const int count = counts[e], off_e = offs[e];

    __shared__ __attribute__((aligned(128))) short A1s0[BM * BK], A1s1[BM * BK], A1s2[BM * BK];
    __shared__ __attribute__((aligned(128))) short A2s0[BM * BK], A2s1[BM * BK], A2s2[BM * BK];
    __shared__ __attribute__((aligned(128))) short B1s0[BN * BK], B1s1[BN * BK], B1s2[BN * BK];
    __shared__ __attribute__((aligned(128))) short B2s0[BN * BK], B2s1[BN * BK], B2s2[BN * BK];
    __shared__ int toks[BM];

    const int tid = threadIdx.x;
    const int lane = tid & 63, wid = tid >> 6;
    const int wr = wid >> 1, wc = wid & 1;
    const int l2 = lane >> 2, la3 = lane & 3, l15 = lane & 15;
    const int kh = (lane >> 4) * 8;

    if (tid < BM) {
        int gr = mbase + tid;
        toks[tid] = (gr < count) ? list[off_e + gr] : -1;
    }
    __syncthreads();

    const int R0 = 16 * wid + l2, R1 = 64 + 16 * wid + l2;
    int t0 = toks[R0]; if (t0 < 0) t0 = 0;
    int t1 = toks[R1]; if (t1 < 0) t1 = 0;
    const unsigned short* sA1_0 = SH + (size_t)t0 * I + la3 * 8;
    const unsigned short* sA1_1 = SH + (size_t)t1 * I + la3 * 8;
    const unsigned short* sA2_0 = RH + (size_t)(off_e + mbase + R0) * I + la3 * 8;
    const unsigned short* sA2_1 = RH + (size_t)(off_e + mbase + R1) * I + la3 * 8;
    const unsigned short* sB1 = WsdT + (size_t)(nb * BN + 16 * wid + l2) * I + la3 * 8;
    const unsigned short* sB2 = dpT + (size_t)e * H * I
                              + (size_t)(nb * BN + 16 * wid + l2) * I + la3 * 8;
    const int wo = wid * 512;

    f32x4 acc[4][2];
#pragma unroll
    for (int i = 0; i < 4; i++)
#pragma unroll
        for (int j = 0; j < 2; j++) acc[i][j] = (f32x4){0.f, 0.f, 0.f, 0.f};

    auto STAGE = [&](short* A1b, short* A2b, short* B1b, short* B2b, int k0) {
        gload16(sA1_0 + k0, A1b + wo); gload16(sA1_1 + k0, A1b + 2048 + wo);
        gload16(sA2_0 + k0, A2b + wo); gload16(sA2_1 + k0, A2b + 2048 + wo);
        gload16(sB1 + k0, B1b + wo);   gload16(sB2 + k0, B2b + wo);
    };
    auto COMPUTE = [&](const short* A1b, const short* A2b, const short* B1b, const short* B2b) {
        bf16x8 af1[4], af2[4], b1[2], b2[2];
#pragma unroll
        for (int q = 0; q < 4; q++) {
            int ro = (wr * 64 + q * 16 + l15) * BK + kh;
            af1[q] = *(const bf16x8*)(A1b + ro);
            af2[q] = *(const bf16x8*)(A2b + ro);
        }
#pragma unroll
        for (int nj = 0; nj < 2; nj++) {
            int ro = (wc * 32 + nj * 16 + l15) * BK + kh;
            b1[nj] = *(const bf16x8*)(B1b + ro);
            b2[nj] = *(const bf16x8*)(B2b + ro);
        }
#pragma unroll
        for (int mi = 0; mi < 4; mi++)
#pragma unroll
            for (int nj = 0; nj < 2; nj++) {
                acc[mi][nj] = __builtin_amdgcn_mfma_f32_16x16x32_bf16(af1[mi], b1[nj], acc[mi][nj], 0, 0, 0);
                acc[mi][nj] = __builtin_amdgcn_mfma_f32_16x16x32_bf16(af2[mi], b2[nj], acc[mi][nj], 0, 0, 0);
            }
    };

    const int nK = I / BK;   // 128
    short *a1c = A1s0, *a1n = A1s1, *a1w = A1s2;
    short *a2c = A2s0, *a2n = A2s1, *a2w = A2s2;
    short *b1c = B1s0, *b1n = B1s1, *b1w = B1s2;
    short *b2c = B2s0, *b2n = B2s1, *b2w = B2s2;
    STAGE(a1c, a2c, b1c, b2c, 0);
    STAGE(a1n, a2n, b1n, b2n, BK);
    for (int kt = 0; kt < nK; kt++) {
        int kf = kt + 2; if (kf >= nK) kf -= nK;
        STAGE(a1w, a2w, b1w, b2w, kf * BK);
        VMCNT12(); BAR();
        COMPUTE(a1c, a2c, b1c, b2c);
        BAR();
        short* t;
        t = a1c; a1c = a1n; a1n = a1w; a1w = t;
        t = a2c; a2c = a2n; a2n = a2w; a2w = t;
        t = b1c; b1c = b1n; b1n = b1w; b1w = t;
        t = b2c; b2c = b2n; b2n = b2w; b2w = t;
    }

    const int rb = (lane >> 4) * 4, cb = l15;
#pragma unroll
    for (int mi = 0; mi < 4; mi++)
#pragma unroll
        for (int nj = 0; nj < 2; nj++) {
            int col = nb * BN + wc * 32 + nj * 16 + cb;
#pragma unroll
            for (int j = 0; j < 4; j++) {
                int lr = wr * 64 + mi * 16 + rb + j;
                int tok = toks[lr];
                if (tok >= 0) out[(size_t)tok * H + col] = acc[mi][nj][j];
            }
        }
}

// ---------------- launcher ----------------

extern "C" void kernel_launch(void* const* d_in, const int* in_sizes, int n_in,
                              void* d_out, int out_size, void* d_ws, size_t ws_size,
                              hipStream_t stream)
{
    const float* x   = (const float*)d_in[0];
    const float* rw  = (const float*)d_in[1];
    const float* gup = (const float*)d_in[2];
    const float* dp  = (const float*)d_in[3];
    const float* sg  = (const float*)d_in[4];
    const float* su  = (const float*)d_in[5];
    const float* sd  = (const float*)d_in[6];

    const int H = 2048, I = 4096, E = 8;
    const int T = in_sizes[0] / H;            // 2048

    float* out        = (float*)d_out;
    float* scores_out = out + (size_t)T * H;  // router_scores [E, T]

    const int slotsCap = T + E * BM;          // 3072
    unsigned short* routedH = (unsigned short*)d_ws;                  // [slotsCap][I]
    unsigned short* sharedH = routedH + (size_t)slotsCap * I;         // [T][I]
    unsigned short* Xbf     = sharedH + (size_t)T * I;                // [T][H]
    unsigned short* XSbf    = Xbf + (size_t)T * H;                    // [slotsCap][H]
    unsigned short* gupT    = XSbf + (size_t)slotsCap * H;            // [E][2I][H]
    unsigned short* dpT     = gupT + (size_t)E * 2 * I * H;           // [E][H][I]
    unsigned short* sgT     = dpT + (size_t)E * H * I;                // [I][H]
    unsigned short* suT     = sgT + (size_t)I * H;                    // [I][H]
    unsigned short* sdT     = suT + (size_t)I * H;                    // [H][I]
    int*   list   = (int*)(sdT + (size_t)H * I);                      // [slotsCap]
    int*   eidx   = list + slotsCap;                                  // [T]
    float* score  = (float*)(eidx + T);                               // [T]
    int*   counts = (int*)(score + T);                                // [E]
    int*   cursor = counts + E;                                       // [E]
    int*   offs   = cursor + E;                                       // [E]
    int*   ntile  = offs + E;                                         // [1]
    int*   tile_e = ntile + 1;                                        // [MAXT]
    int*   tile_m = tile_e + MAXT;                                    // [MAXT]

    const int maxRTiles = T / BM + E;         // 24
    const int maxUTiles = T / BM + maxRTiles; // 40

    // weight prep (independent of routing)
    transpose_cvt<<<dim3(H / 64, I / 64, 1), 256, 0, stream>>>(sg, sgT, H, I);
    transpose_cvt<<<dim3(H / 64, I / 64, 1), 256, 0, stream>>>(su, suT, H, I);
    transpose_cvt<<<dim3(I / 64, H / 64, 1), 256, 0, stream>>>(sd, sdT, I, H);
    transpose_cvt<<<dim3(H / 64, (2 * I) / 64, E), 256, 0, stream>>>(gup, gupT, H, 2 * I);
    transpose_cvt<<<dim3(I / 64, H / 64, E), 256, 0, stream>>>(dp, dpT, I, H);

    // routing
    hipMemsetAsync(counts, 0, 2 * E * sizeof(int), stream);
    router_kernel<<<(T * E) / 256, 256, 0, stream>>>(x, rw, scores_out, eidx, score, counts, T, H, E);
    prefix_kernel<<<1, 1, 0, stream>>>(counts, offs, tile_e, tile_m, ntile, E);
    scatter_kernel<<<(T + 255) / 256, 256, 0, stream>>>(eidx, offs, cursor, list, T);
    prep_x<<<T + slotsCap, 256, 0, stream>>>(x, list, score, counts, offs, Xbf, XSbf, T, H, E);

    // GEMMs
    up_gemm<<<dim3(maxUTiles, I / BN), 256, 0, stream>>>(Xbf, XSbf, sgT, suT, gupT,
                                                         tile_e, tile_m, ntile, offs,
                                                         sharedH, routedH, I, T);
    fused_down<<<dim3(maxRTiles, H / BN), 256, 0, stream>>>(sharedH, routedH, sdT, dpT,
                                                            counts, offs, list,
                                                            tile_e, tile_m, ntile, out, I, H);
}

// Round 10
// 932.796 us; speedup vs baseline: 1.0077x; 1.0077x over previous
//
#include <hip/hip_runtime.h>
#include <math.h>

// Llama4TextMoe — round 10: r7 structure + CORRECT minimal 2-phase pipeline.
// K-loop: STAGE(other buf, kt+1) -> COMPUTE(cur: ds_read_b128 frags + MFMA)
//         -> vmcnt(0) -> s_barrier -> swap.
// DMA for tile kt+1 flies UNDER compute of tile kt (r8/r9 drained before compute
// — wrong). One barrier per K-step: per-wave vmcnt(0) before the barrier means
// barrier-release implies all waves' next-buf DMAs landed; ds_reads of cur
// complete before each wave's MFMAs, so post-barrier overwrite is race-free.
// prep (validated r7): weights fp32[K][N] -> bf16[N][K]; X/XS -> bf16 slot-ordered.

#define BM 128
#define BN 64
#define BK 32
#define MAXT 32

typedef float f32x4 __attribute__((ext_vector_type(4)));
typedef short bf16x8 __attribute__((ext_vector_type(8)));
typedef __bf16 bf2 __attribute__((ext_vector_type(2)));

__device__ inline unsigned int pk2(float a, float b) {
    union { bf2 h; unsigned int u; } c;
    c.h[0] = (__bf16)a; c.h[1] = (__bf16)b;   // v_cvt_pk_bf16_f32
    return c.u;
}
__device__ inline unsigned short f2bf(float a) {
    union { __bf16 h; unsigned short u; } c; c.h = (__bf16)a; return c.u;
}
__device__ inline bf16x8 pk8(float4 a, float4 b) {
    union { bf16x8 v; unsigned int u[4]; } c;
    c.u[0] = pk2(a.x, a.y); c.u[1] = pk2(a.z, a.w);
    c.u[2] = pk2(b.x, b.y); c.u[3] = pk2(b.z, b.w);
    return c.v;
}

// global -> LDS DMA, 16B per lane; dest = (wave-uniform lds) + lane*16.
__device__ inline void gload16(const void* g, void* l) {
    __builtin_amdgcn_global_load_lds(
        (const __attribute__((address_space(1))) void*)(unsigned long long)g,
        (__attribute__((address_space(3))) void*)(unsigned int)(unsigned long long)l,
        16, 0, 0);
}

#define VMCNT0() asm volatile("s_waitcnt vmcnt(0)" ::: "memory")
#define BAR()    __builtin_amdgcn_s_barrier()

// ---------------- router / bookkeeping (validated) ----------------

__global__ __launch_bounds__(256) void router_kernel(
    const float* __restrict__ x, const float* __restrict__ rw,
    float* __restrict__ scores_out, int* __restrict__ eidx,
    float* __restrict__ score, int* __restrict__ counts, int T, int H, int E)
{
    int g = blockIdx.x * 256 + threadIdx.x;
    int t = g >> 3, e = g & 7;          // E == 8
    if (t >= T) return;
    const float4* xr4 = (const float4*)(x + (size_t)t * H);
    float acc = 0.f;
    for (int k4 = 0; k4 < H / 4; k4++) {
        float4 xv = xr4[k4];
        int k = 4 * k4;
        acc = fmaf(xv.x, rw[(k + 0) * E + e], acc);
        acc = fmaf(xv.y, rw[(k + 1) * E + e], acc);
        acc = fmaf(xv.z, rw[(k + 2) * E + e], acc);
        acc = fmaf(xv.w, rw[(k + 3) * E + e], acc);
    }
    float bv = acc; int bi = e;
    #pragma unroll
    for (int off = 4; off; off >>= 1) {
        float ov = __shfl_xor(bv, off, 8);
        int   oi = __shfl_xor(bi, off, 8);
        if (ov > bv || (ov == bv && oi < bi)) { bv = ov; bi = oi; }
    }
    float sig = 1.f / (1.f + __expf(-bv));
    scores_out[(size_t)e * T + t] = (e == bi) ? sig : 0.f;
    if (e == 0) {
        eidx[t] = bi;
        score[t] = sig;
        atomicAdd(&counts[bi], 1);
    }
}

__global__ void prefix_kernel(const int* __restrict__ counts, int* __restrict__ offs,
                              int* __restrict__ tile_e, int* __restrict__ tile_m,
                              int* __restrict__ ntile, int E)
{
    if (blockIdx.x == 0 && threadIdx.x == 0) {
        int run = 0, nt = 0;
        for (int e = 0; e < E; e++) {
            offs[e] = run;
            int c = counts[e];
            int t = (c + BM - 1) / BM;
            for (int i = 0; i < t; i++) { tile_e[nt] = e; tile_m[nt] = i * BM; nt++; }
            run += t * BM;
        }
        ntile[0] = nt;
    }
}

__global__ __launch_bounds__(256) void scatter_kernel(
    const int* __restrict__ eidx, const int* __restrict__ offs,
    int* __restrict__ cursor, int* __restrict__ list, int T)
{
    int t = blockIdx.x * 256 + threadIdx.x;
    if (t >= T) return;
    int e = eidx[t];
    int pos = offs[e] + atomicAdd(&cursor[e], 1);
    list[pos] = t;
}

// ---------------- prep: X -> bf16, XS (slot-ordered, scaled) -> bf16 ----------------

__global__ __launch_bounds__(256) void prep_x(
    const float* __restrict__ x, const int* __restrict__ list,
    const float* __restrict__ score, const int* __restrict__ counts,
    const int* __restrict__ offs,
    unsigned short* __restrict__ Xbf, unsigned short* __restrict__ XSbf,
    int T, int H, int E)
{
    int bid = blockIdx.x, tid = threadIdx.x;   // one block = one row; H/8 == 256
    if (bid < T) {
        const float* src = x + (size_t)bid * H + tid * 8;
        float4 a = *(const float4*)src, b = *(const float4*)(src + 4);
        *(bf16x8*)(Xbf + (size_t)bid * H + tid * 8) = pk8(a, b);
    } else {
        int s = bid - T;
        int tok = -1; float sc = 0.f;
        for (int e = 0; e < E; e++) {
            int pad = ((counts[e] + BM - 1) / BM) * BM;
            if (s >= offs[e] && s < offs[e] + pad) {
                if (s - offs[e] < counts[e]) { tok = list[s]; sc = score[tok]; }
                break;
            }
        }
        bf16x8 o;
        if (tok >= 0) {
            const float* src = x + (size_t)tok * H + tid * 8;
            float4 a = *(const float4*)src, b = *(const float4*)(src + 4);
            a.x *= sc; a.y *= sc; a.z *= sc; a.w *= sc;
            b.x *= sc; b.y *= sc; b.z *= sc; b.w *= sc;
            o = pk8(a, b);
        } else {
            o = (bf16x8){0,0,0,0,0,0,0,0};
        }
        *(bf16x8*)(XSbf + (size_t)s * H + tid * 8) = o;
    }
}

// ---------------- prep: W fp32 [B][K][N] -> bf16 [B][N][K] ----------------

__global__ __launch_bounds__(256) void transpose_cvt(
    const float* __restrict__ src, unsigned short* __restrict__ dst, int K, int N)
{
    __shared__ float t[64][65];
    src += (size_t)blockIdx.z * K * N;
    dst += (size_t)blockIdx.z * K * N;
    const int k0 = blockIdx.x * 64, n0 = blockIdx.y * 64;
    const int tid = threadIdx.x;
    const int r = tid >> 4, c = (tid & 15) * 4;
#pragma unroll
    for (int i = 0; i < 4; i++) {
        float4 v = *(const float4*)(src + (size_t)(k0 + r + 16 * i) * N + n0 + c);
        t[r + 16 * i][c + 0] = v.x; t[r + 16 * i][c + 1] = v.y;
        t[r + 16 * i][c + 2] = v.z; t[r + 16 * i][c + 3] = v.w;
    }
    __syncthreads();
    const int nl = tid >> 2, kq = (tid & 3) * 16;
    union { bf16x8 v[2]; unsigned short u[16]; } o;
#pragma unroll
    for (int j = 0; j < 16; j++) o.u[j] = f2bf(t[kq + j][nl]);
    unsigned short* d = dst + (size_t)(n0 + nl) * K + k0 + kq;
    *(bf16x8*)d = o.v[0];
    *(bf16x8*)(d + 8) = o.v[1];
}

// ---------------- up: merged shared+routed, minimal 2-phase ----------------

__global__ __launch_bounds__(256) void up_gemm(
    const unsigned short* __restrict__ Xbf, const unsigned short* __restrict__ XSbf,
    const unsigned short* __restrict__ sgT, const unsigned short* __restrict__ suT,
    const unsigned short* __restrict__ gupT,
    const int* __restrict__ tile_e, const int* __restrict__ tile_m,
    const int* __restrict__ ntile, const int* __restrict__ offs,
    unsigned short* __restrict__ sharedH, unsigned short* __restrict__ routedH,
    int I, int T)
{
    const int K = 2048;
    const int nwg = gridDim.x * gridDim.y;
    const int hw = blockIdx.y * gridDim.x + blockIdx.x;
    const int q8 = nwg >> 3;                         // nwg % 8 == 0 by construction
    const int vid = (hw & 7) * q8 + (hw >> 3);
    const int gt = vid % gridDim.x;
    const int nb = vid / gridDim.x;
    const int TS = T / BM;

    const unsigned short *Ab, *Bg, *Bu;
    unsigned short* outP;
    int rowbase;
    if (gt < TS) {
        Ab = Xbf + (size_t)(gt * BM) * K;
        Bg = sgT + (size_t)(nb * BN) * K;
        Bu = suT + (size_t)(nb * BN) * K;
        rowbase = gt * BM; outP = sharedH;
    } else {
        int idx = gt - TS;
        if (idx >= ntile[0]) return;
        int e = tile_e[idx], mb = tile_m[idx], oe = offs[e];
        Ab = XSbf + (size_t)(oe + mb) * K;
        const unsigned short* W = gupT + (size_t)e * (2 * (size_t)I) * K;
        Bg = W + (size_t)(nb * BN) * K;
        Bu = W + (size_t)(I + nb * BN) * K;
        rowbase = oe + mb; outP = routedH;
    }

    __shared__ __attribute__((aligned(128))) short As0[BM * BK], As1[BM * BK];
    __shared__ __attribute__((aligned(128))) short Gs0[BN * BK], Gs1[BN * BK];
    __shared__ __attribute__((aligned(128))) short Us0[BN * BK], Us1[BN * BK];

    const int tid = threadIdx.x;
    const int lane = tid & 63, wid = tid >> 6;
    const int wr = wid >> 1, wc = wid & 1;
    const int l2 = lane >> 2, la3 = lane & 3, l15 = lane & 15;
    const int kh = (lane >> 4) * 8;

    const unsigned short* sA0 = Ab + (size_t)(16 * wid + l2) * K + la3 * 8;
    const unsigned short* sA1 = Ab + (size_t)(64 + 16 * wid + l2) * K + la3 * 8;
    const unsigned short* sG  = Bg + (size_t)(16 * wid + l2) * K + la3 * 8;
    const unsigned short* sU  = Bu + (size_t)(16 * wid + l2) * K + la3 * 8;
    const int wo = wid * 512;

    f32x4 accg[4][2], accu[4][2];
#pragma unroll
    for (int i = 0; i < 4; i++)
#pragma unroll
        for (int j = 0; j < 2; j++) {
            accg[i][j] = (f32x4){0.f, 0.f, 0.f, 0.f};
            accu[i][j] = (f32x4){0.f, 0.f, 0.f, 0.f};
        }

    auto STAGE = [&](short* Ab_, short* Gb_, short* Ub_, int k0) {
        gload16(sA0 + k0, Ab_ + wo); gload16(sA1 + k0, Ab_ + 2048 + wo);
        gload16(sG + k0, Gb_ + wo);  gload16(sU + k0, Ub_ + wo);
    };
    auto COMPUTE = [&](const short* Asb, const short* Gsb, const short* Usb) {
        bf16x8 af[4], gfr[2], ufr[2];
#pragma unroll
        for (int q = 0; q < 4; q++)
            af[q] = *(const bf16x8*)(Asb + (wr * 64 + q * 16 + l15) * BK + kh);
#pragma unroll
        for (int nj = 0; nj < 2; nj++) {
            gfr[nj] = *(const bf16x8*)(Gsb + (wc * 32 + nj * 16 + l15) * BK + kh);
            ufr[nj] = *(const bf16x8*)(Usb + (wc * 32 + nj * 16 + l15) * BK + kh);
        }
#pragma unroll
        for (int mi = 0; mi < 4; mi++)
#pragma unroll
            for (int nj = 0; nj < 2; nj++) {
                accg[mi][nj] = __builtin_amdgcn_mfma_f32_16x16x32_bf16(af[mi], gfr[nj], accg[mi][nj], 0, 0, 0);
                accu[mi][nj] = __builtin_amdgcn_mfma_f32_16x16x32_bf16(af[mi], ufr[nj], accu[mi][nj], 0, 0, 0);
            }
    };

    const int nK = K / BK;   // 64 (even)
    STAGE(As0, Gs0, Us0, 0);
    VMCNT0(); BAR();
    for (int kt = 0; kt < nK; kt += 2) {
        // phase A: issue tile kt+1 into buf1, compute buf0 under the DMA
        if (kt + 1 < nK) STAGE(As1, Gs1, Us1, (kt + 1) * BK);
        COMPUTE(As0, Gs0, Us0);
        VMCNT0(); BAR();
        // phase B: issue tile kt+2 into buf0, compute buf1
        if (kt + 2 < nK) STAGE(As0, Gs0, Us0, (kt + 2) * BK);
        COMPUTE(As1, Gs1, Us1);
        VMCNT0(); BAR();
    }

    const int rb = (lane >> 4) * 4, cb = l15;
#pragma unroll
    for (int mi = 0; mi < 4; mi++)
#pragma unroll
        for (int nj = 0; nj < 2; nj++) {
            int col = nb * BN + wc * 32 + nj * 16 + cb;
#pragma unroll
            for (int j = 0; j < 4; j++) {
                float g = accg[mi][nj][j], u = accu[mi][nj][j];
                float r = u * g * __builtin_amdgcn_rcpf(1.f + __expf(-g));
                int row = rowbase + wr * 64 + mi * 16 + rb + j;
                outP[(size_t)row * I + col] = f2bf(r);
            }
        }
}

// ---------------- fused down: out[tok] = SH[tok]@WsdT^T + RH[slot]@dpT_e^T ----------------

__global__ __launch_bounds__(256) void fused_down(
    const unsigned short* __restrict__ SH, const unsigned short* __restrict__ RH,
    const unsigned short* __restrict__ WsdT, const unsigned short* __restrict__ dpT,
    const int* __restrict__ counts, const int* __restrict__ offs,
    const int* __restrict__ list,
    const int* __restrict__ tile_e, const int* __restrict__ tile_m,
    const int* __restrict__ ntile,
    float* __restrict__ out, int I, int H)
{
    const int nwg = gridDim.x * gridDim.y;
    const int hw = blockIdx.y * gridDim.x + blockIdx.x;
    const int q8 = nwg >> 3;
    const int vid = (hw & 7) * q8 + (hw >> 3);
    const int gt = vid % gridDim.x;
    const int nb = vid / gridDim.x;
    if (gt >= ntile[0]) return;
    const int e = tile_e[gt], mbase = tile_m[gt];
    const int count = counts[e], off_e = offs[e];

    __shared__ __attribute__((aligned(128))) short A1s0[BM * BK], A1s1[BM * BK];
    __shared__ __attribute__((aligned(128))) short A2s0[BM * BK], A2s1[BM * BK];
    __shared__ __attribute__((aligned(128))) short B1s0[BN * BK], B1s1[BN * BK];
    __shared__ __attribute__((aligned(128))) short B2s0[BN * BK], B2s1[BN * BK];
    __shared__ int toks[BM];

    const int tid = threadIdx.x;
    const int lane = tid & 63, wid = tid >> 6;
    const int wr = wid >> 1, wc = wid & 1;
    const int l2 = lane >> 2, la3 = lane & 3, l15 = lane & 15;
    const int kh = (lane >> 4) * 8;

    if (tid < BM) {
        int gr = mbase + tid;
        toks[tid] = (gr < count) ? list[off_e + gr] : -1;
    }
    __syncthreads();

    const int R0 = 16 * wid + l2, R1 = 64 + 16 * wid + l2;
    int t0 = toks[R0]; if (t0 < 0) t0 = 0;
    int t1 = toks[R1]; if (t1 < 0) t1 = 0;
    const unsigned short* sA1_0 = SH + (size_t)t0 * I + la3 * 8;
    const unsigned short* sA1_1 = SH + (size_t)t1 * I + la3 * 8;
    const unsigned short* sA2_0 = RH + (size_t)(off_e + mbase + R0) * I + la3 * 8;
    const unsigned short* sA2_1 = RH + (size_t)(off_e + mbase + R1) * I + la3 * 8;
    const unsigned short* sB1 = WsdT + (size_t)(nb * BN + 16 * wid + l2) * I + la3 * 8;
    const unsigned short* sB2 = dpT + (size_t)e * H * I
                              + (size_t)(nb * BN + 16 * wid + l2) * I + la3 * 8;
    const int wo = wid * 512;

    f32x4 acc[4][2];
#pragma unroll
    for (int i = 0; i < 4; i++)
#pragma unroll
        for (int j = 0; j < 2; j++) acc[i][j] = (f32x4){0.f, 0.f, 0.f, 0.f};

    auto STAGE = [&](short* A1b, short* A2b, short* B1b, short* B2b, int k0) {
        gload16(sA1_0 + k0, A1b + wo); gload16(sA1_1 + k0, A1b + 2048 + wo);
        gload16(sA2_0 + k0, A2b + wo); gload16(sA2_1 + k0, A2b + 2048 + wo);
        gload16(sB1 + k0, B1b + wo);   gload16(sB2 + k0, B2b + wo);
    };
    auto COMPUTE = [&](const short* A1b, const short* A2b, const short* B1b, const short* B2b) {
        bf16x8 af1[4], af2[4], b1[2], b2[2];
#pragma unroll
        for (int q = 0; q < 4; q++) {
            int ro = (wr * 64 + q * 16 + l15) * BK + kh;
            af1[q] = *(const bf16x8*)(A1b + ro);
            af2[q] = *(const bf16x8*)(A2b + ro);
        }
#pragma unroll
        for (int nj = 0; nj < 2; nj++) {
            int ro = (wc * 32 + nj * 16 + l15) * BK + kh;
            b1[nj] = *(const bf16x8*)(B1b + ro);
            b2[nj] = *(const bf16x8*)(B2b + ro);
        }
#pragma unroll
        for (int mi = 0; mi < 4; mi++)
#pragma unroll
            for (int nj = 0; nj < 2; nj++) {
                acc[mi][nj] = __builtin_amdgcn_mfma_f32_16x16x32_bf16(af1[mi], b1[nj], acc[mi][nj], 0, 0, 0);
                acc[mi][nj] = __builtin_amdgcn_mfma_f32_16x16x32_bf16(af2[mi], b2[nj], acc[mi][nj], 0, 0, 0);
            }
    };

    const int nK = I / BK;   // 128 (even)
    STAGE(A1s0, A2s0, B1s0, B2s0, 0);
    VMCNT0(); BAR();
    for (int kt = 0; kt < nK; kt += 2) {
        if (kt + 1 < nK) STAGE(A1s1, A2s1, B1s1, B2s1, (kt + 1) * BK);
        COMPUTE(A1s0, A2s0, B1s0, B2s0);
        VMCNT0(); BAR();
        if (kt + 2 < nK) STAGE(A1s0, A2s0, B1s0, B2s0, (kt + 2) * BK);
        COMPUTE(A1s1, A2s1, B1s1, B2s1);
        VMCNT0(); BAR();
    }

    const int rb = (lane >> 4) * 4, cb = l15;
#pragma unroll
    for (int mi = 0; mi < 4; mi++)
#pragma unroll
        for (int nj = 0; nj < 2; nj++) {
            int col = nb * BN + wc * 32 + nj * 16 + cb;
#pragma unroll
            for (int j = 0; j < 4; j++) {
                int lr = wr * 64 + mi * 16 + rb + j;
                int tok = toks[lr];
                if (tok >= 0) out[(size_t)tok * H + col] = acc[mi][nj][j];
            }
        }
}

// ---------------- launcher ----------------

extern "C" void kernel_launch(void* const* d_in, const int* in_sizes, int n_in,
                              void* d_out, int out_size, void* d_ws, size_t ws_size,
                              hipStream_t stream)
{
    const float* x   = (const float*)d_in[0];
    const float* rw  = (const float*)d_in[1];
    const float* gup = (const float*)d_in[2];
    const float* dp  = (const float*)d_in[3];
    const float* sg  = (const float*)d_in[4];
    const float* su  = (const float*)d_in[5];
    const float* sd  = (const float*)d_in[6];

    const int H = 2048, I = 4096, E = 8;
    const int T = in_sizes[0] / H;            // 2048

    float* out        = (float*)d_out;
    float* scores_out = out + (size_t)T * H;  // router_scores [E, T]

    const int slotsCap = T + E * BM;          // 3072
    unsigned short* routedH = (unsigned short*)d_ws;                  // [slotsCap][I]
    unsigned short* sharedH = routedH + (size_t)slotsCap * I;         // [T][I]
    unsigned short* Xbf     = sharedH + (size_t)T * I;                // [T][H]
    unsigned short* XSbf    = Xbf + (size_t)T * H;                    // [slotsCap][H]
    unsigned short* gupT    = XSbf + (size_t)slotsCap * H;            // [E][2I][H]
    unsigned short* dpT     = gupT + (size_t)E * 2 * I * H;           // [E][H][I]
    unsigned short* sgT     = dpT + (size_t)E * H * I;                // [I][H]
    unsigned short* suT     = sgT + (size_t)I * H;                    // [I][H]
    unsigned short* sdT     = suT + (size_t)I * H;                    // [H][I]
    int*   list   = (int*)(sdT + (size_t)H * I);                      // [slotsCap]
    int*   eidx   = list + slotsCap;                                  // [T]
    float* score  = (float*)(eidx + T);                               // [T]
    int*   counts = (int*)(score + T);                                // [E]
    int*   cursor = counts + E;                                       // [E]
    int*   offs   = cursor + E;                                       // [E]
    int*   ntile  = offs + E;                                         // [1]
    int*   tile_e = ntile + 1;                                        // [MAXT]
    int*   tile_m = tile_e + MAXT;                                    // [MAXT]

    const int maxRTiles = T / BM + E;         // 24
    const int maxUTiles = T / BM + maxRTiles; // 40

    // weight prep (independent of routing)
    transpose_cvt<<<dim3(H / 64, I / 64, 1), 256, 0, stream>>>(sg, sgT, H, I);
    transpose_cvt<<<dim3(H / 64, I / 64, 1), 256, 0, stream>>>(su, suT, H, I);
    transpose_cvt<<<dim3(I / 64, H / 64, 1), 256, 0, stream>>>(sd, sdT, I, H);
    transpose_cvt<<<dim3(H / 64, (2 * I) / 64, E), 256, 0, stream>>>(gup, gupT, H, 2 * I);
    transpose_cvt<<<dim3(I / 64, H / 64, E), 256, 0, stream>>>(dp, dpT, I, H);

    // routing
    hipMemsetAsync(counts, 0, 2 * E * sizeof(int), stream);
    router_kernel<<<(T * E) / 256, 256, 0, stream>>>(x, rw, scores_out, eidx, score, counts, T, H, E);
    prefix_kernel<<<1, 1, 0, stream>>>(counts, offs, tile_e, tile_m, ntile, E);
    scatter_kernel<<<(T + 255) / 256, 256, 0, stream>>>(eidx, offs, cursor, list, T);
    prep_x<<<T + slotsCap, 256, 0, stream>>>(x, list, score, counts, offs, Xbf, XSbf, T, H, E);

    // GEMMs
    up_gemm<<<dim3(maxUTiles, I / BN), 256, 0, stream>>>(Xbf, XSbf, sgT, suT, gupT,
                                                         tile_e, tile_m, ntile, offs,
                                                         sharedH, routedH, I, T);
    fused_down<<<dim3(maxRTiles, H / BN), 256, 0, stream>>>(sharedH, routedH, sdT, dpT,
                                                            counts, offs, list,
                                                            tile_e, tile_m, ntile, out, I, H);
}